// Round 2
// baseline (554.182 us; speedup 1.0000x reference)
//
#include <hip/hip_runtime.h>

#define N_ROIS 1024
#define FEAT   1024
#define GRP    16
#define DG     64
#define EMB    64

typedef __attribute__((ext_vector_type(8))) short short8;   // 8 bf16 = 4 VGPR (MFMA A/B frag)
typedef __attribute__((ext_vector_type(4))) float f32x4;    // MFMA C/D frag
typedef unsigned short u16;
typedef unsigned int   u32;
typedef __attribute__((ext_vector_type(8))) u16 u16x8;

__device__ __forceinline__ u16 f2bf(float x) {              // RNE f32->bf16
  u32 u = __float_as_uint(x);
  u = (u + 0x7fff + ((u >> 16) & 1)) >> 16;
  return (u16)u;
}
__device__ __forceinline__ float bf2f(u16 h) {
  return __uint_as_float(((u32)h) << 16);
}

// async global->LDS, 16B per lane. LDS dest is wave-uniform base (+lane*16 in HW).
__device__ __forceinline__ void gload_lds16(const void* g, void* l) {
  __builtin_amdgcn_global_load_lds(
      (__attribute__((address_space(1))) const u32*)g,
      (__attribute__((address_space(3))) u32*)l, 16, 0, 0);
}

// ---------------- K0a: f32 -> bf16 for roi, q_w, k_w, out_w ----------------
__global__ __launch_bounds__(256) void cvt_kernel(
    const float* __restrict__ s0, const float* __restrict__ s1,
    const float* __restrict__ s2, const float* __restrict__ s3,
    u16* __restrict__ d0, u16* __restrict__ d1,
    u16* __restrict__ d2, u16* __restrict__ d3)
{
  long id = (long)blockIdx.x * 256 + threadIdx.x;   // 1M float4 units total
  int seg = (int)(id >> 18);                        // 256K units per array
  long off = (id & 0x3ffff) * 4;
  const float* s = seg == 0 ? s0 : seg == 1 ? s1 : seg == 2 ? s2 : s3;
  u16* d       = seg == 0 ? d0 : seg == 1 ? d1 : seg == 2 ? d2 : d3;
  float4 v = *(const float4*)(s + off);
  ushort4 o;
  o.x = f2bf(v.x); o.y = f2bf(v.y); o.z = f2bf(v.z); o.w = f2bf(v.w);
  *(ushort4*)(d + off) = o;
}

// ---------------- K0b: roiT_bf[f][m] = bf16(roi[m][f]) ----------------
__global__ __launch_bounds__(256) void transpose_kernel(
    const float* __restrict__ in, u16* __restrict__ out)
{
  __shared__ float tile[64][65];                    // +1 pad: conflict-free
  const int t = threadIdx.x;
  const long r0 = (long)blockIdx.x * 64;
  const long c0 = (long)blockIdx.y * 64;
  #pragma unroll
  for (int p = 0; p < 4; ++p) {
    int i = (t >> 4) + p * 16;
    int j = (t & 15) * 4;
    float4 v = *(const float4*)(in + (r0 + i) * FEAT + c0 + j);
    tile[i][j] = v.x; tile[i][j + 1] = v.y; tile[i][j + 2] = v.z; tile[i][j + 3] = v.w;
  }
  __syncthreads();
  const int j = t >> 2;                             // output row (input col)
  const int i0 = (t & 3) * 16;
  u16x8 a, b;
  #pragma unroll
  for (int i = 0; i < 8; ++i) a[i] = f2bf(tile[i0 + i][j]);
  #pragma unroll
  for (int i = 0; i < 8; ++i) b[i] = f2bf(tile[i0 + 8 + i][j]);
  u16x8* dst = (u16x8*)(out + (c0 + j) * N_ROIS + r0 + i0);
  dst[0] = a; dst[1] = b;
}

// ---------------- generic bf16 MFMA GEMM: C = (A * B^T + bias) * scale -----
// A: MxK row-major (lda), B: NxK row-major (ldb), both bf16.
// 256 thr = 4 waves in 2x2; wave tile (BM/2)x(BN/2); 16x16x32 MFMA frags.
// LDS tiles BMx64 / BNx64, rows 128B; XOR swizzle chunk ^= (row&7) so the
// linear global_load_lds staging and the ds_read_b128 frag reads are both
// conflict-free (source pre-swizzled, read swizzled: both-sides rule; note
// frag row&7 == lane&7 so the read XOR uses lane&7).
template<int BM, int BN>
__global__ __launch_bounds__(256) void gemm_kernel(
    const u16* __restrict__ A, long lda, long Az,
    const u16* __restrict__ B, long ldb, long Bz,
    void* __restrict__ Cv, long ldc, long Cz, int c_bf16,
    const float* __restrict__ bias, long biasz,
    float scale, int K)
{
  constexpr int BK = 64;
  constexpr int WM = BM / 2, WN = BN / 2;
  constexpr int FM = WM / 16, FN = WN / 16;
  __shared__ u16 lA[BM * BK];
  __shared__ u16 lB[BN * BK];
  const int t = threadIdx.x;
  const int lane = t & 63;
  const int wave = t >> 6;
  const int wr = wave >> 1, wc = wave & 1;
  const long m0 = (long)blockIdx.x * BM;
  const long n0 = (long)blockIdx.y * BN;
  const int z = blockIdx.z;
  const u16* Ab = A + z * Az + m0 * lda;
  const u16* Bb = B + z * Bz + n0 * ldb;

  f32x4 acc[FM][FN];
  #pragma unroll
  for (int i = 0; i < FM; ++i)
    #pragma unroll
    for (int j = 0; j < FN; ++j)
      acc[i][j] = (f32x4){0.f, 0.f, 0.f, 0.f};

  for (int kk = 0; kk < K; kk += BK) {
    __syncthreads();
    #pragma unroll
    for (int qq = 0; qq < BM / 32; ++qq) {          // stage A (4KB per issue)
      int off = qq * 4096 + t * 16;
      int row = off >> 7;                           // 128B rows
      int sc = (t & 7) ^ (row & 7);                 // pre-swizzled source chunk
      gload_lds16(Ab + (long)row * lda + kk + sc * 8,
                  (char*)lA + qq * 4096 + (t & ~63) * 16);
    }
    #pragma unroll
    for (int qq = 0; qq < BN / 32; ++qq) {          // stage B
      int off = qq * 4096 + t * 16;
      int row = off >> 7;
      int sc = (t & 7) ^ (row & 7);
      gload_lds16(Bb + (long)row * ldb + kk + sc * 8,
                  (char*)lB + qq * 4096 + (t & ~63) * 16);
    }
    __syncthreads();                                // drains vmcnt before use
    #pragma unroll
    for (int ks = 0; ks < 2; ++ks) {                // two K=32 steps
      short8 af[FM], bfr[FN];
      #pragma unroll
      for (int i = 0; i < FM; ++i) {
        int row = wr * WM + i * 16 + (lane & 15);
        int sc = (ks * 4 + (lane >> 4)) ^ (lane & 7);
        af[i] = *(const short8*)((const char*)lA + row * 128 + sc * 16);
      }
      #pragma unroll
      for (int j = 0; j < FN; ++j) {
        int row = wc * WN + j * 16 + (lane & 15);
        int sc = (ks * 4 + (lane >> 4)) ^ (lane & 7);
        bfr[j] = *(const short8*)((const char*)lB + row * 128 + sc * 16);
      }
      #pragma unroll
      for (int i = 0; i < FM; ++i)
        #pragma unroll
        for (int j = 0; j < FN; ++j)
          acc[i][j] = __builtin_amdgcn_mfma_f32_16x16x32_bf16(af[i], bfr[j], acc[i][j], 0, 0, 0);
    }
  }

  const float* bz = bias ? bias + z * biasz : nullptr;
  #pragma unroll
  for (int i = 0; i < FM; ++i) {
    #pragma unroll
    for (int j = 0; j < FN; ++j) {
      long col = n0 + wc * WN + j * 16 + (lane & 15);
      float b = bz ? bz[col] : 0.f;
      #pragma unroll
      for (int r = 0; r < 4; ++r) {                 // D: row=(l>>4)*4+r, col=l&15
        long row = m0 + wr * WM + i * 16 + (lane >> 4) * 4 + r;
        float v = (acc[i][j][r] + b) * scale;
        long idx = row * ldc + col + (long)z * Cz;
        if (c_bf16) ((u16*)Cv)[idx] = f2bf(v);
        else        ((float*)Cv)[idx] = v;
      }
    }
  }
}

// ---------------- K2a: aff[g][n][m] = sum_d q'[n][g*64+d] * k[m][g*64+d] ----
// q' already scaled by 1/8. K=64 -> 2 MFMAs; frags loaded directly (q,k are L2-hot).
__global__ __launch_bounds__(256) void aff_kernel(
    const u16* __restrict__ q, const u16* __restrict__ k, u16* __restrict__ aff)
{
  const int t = threadIdx.x;
  const int lane = t & 63;
  const int wave = t >> 6;
  const int g = blockIdx.z;
  const long n0 = (long)blockIdx.x * 64 + wave * 16;
  const long m0 = (long)blockIdx.y * 64;
  const u16* qp = q + (n0 + (lane & 15)) * (GRP * DG) + g * DG + (lane >> 4) * 8;
  short8 a0 = *(const short8*)qp;
  short8 a1 = *(const short8*)(qp + 32);
  f32x4 acc[4];
  #pragma unroll
  for (int mt = 0; mt < 4; ++mt) acc[mt] = (f32x4){0.f, 0.f, 0.f, 0.f};
  #pragma unroll
  for (int mt = 0; mt < 4; ++mt) {
    const u16* kp = k + (m0 + mt * 16 + (lane & 15)) * (GRP * DG) + g * DG + (lane >> 4) * 8;
    short8 b0 = *(const short8*)kp;
    short8 b1 = *(const short8*)(kp + 32);
    acc[mt] = __builtin_amdgcn_mfma_f32_16x16x32_bf16(a0, b0, acc[mt], 0, 0, 0);
    acc[mt] = __builtin_amdgcn_mfma_f32_16x16x32_bf16(a1, b1, acc[mt], 0, 0, 0);
  }
  #pragma unroll
  for (int mt = 0; mt < 4; ++mt)
    #pragma unroll
    for (int r = 0; r < 4; ++r) {
      long n = n0 + (lane >> 4) * 4 + r;
      long m = m0 + mt * 16 + (lane & 15);
      aff[((long)g << 20) + (n << 10) + m] = f2bf(acc[mt][r]);
    }
}

// ---------------- K2b: pf + relu + log + aff -> softmax -> S (bf16) --------
// One block per n. pe is read exactly once across the grid (268MB = the floor).
// Thread t owns m in [4t,4t+4) for ALL 16 groups; softmax reduced via shfl+LDS.
__global__ __launch_bounds__(256) void softmax_kernel(
    const float* __restrict__ pe, const float* __restrict__ pos_w,
    const float* __restrict__ pos_b, const u16* __restrict__ aff,
    u16* __restrict__ S)
{
  __shared__ float pw[GRP * EMB];
  __shared__ float red[GRP][4];
  const int t = threadIdx.x;
  const int lane = t & 63;
  const int wave = t >> 6;
  const long n = blockIdx.x;
  const int m0 = t * 4;

  for (int i = t; i < GRP * EMB; i += 256) pw[i] = pos_w[i];

  float acc[GRP][4];
  #pragma unroll
  for (int c = 0; c < GRP; ++c) {
    float b = pos_b[c];
    acc[c][0] = b; acc[c][1] = b; acc[c][2] = b; acc[c][3] = b;
  }
  __syncthreads();

  for (int e = 0; e < EMB; ++e) {
    float4 pv = *(const float4*)(pe + ((long)e * N_ROIS + n) * N_ROIS + m0);
    #pragma unroll
    for (int c = 0; c < GRP; ++c) {
      float w = pw[c * EMB + e];                    // broadcast, conflict-free
      acc[c][0] = fmaf(w, pv.x, acc[c][0]);
      acc[c][1] = fmaf(w, pv.y, acc[c][1]);
      acc[c][2] = fmaf(w, pv.z, acc[c][2]);
      acc[c][3] = fmaf(w, pv.w, acc[c][3]);
    }
  }

  // logits = log(max(relu(pf),1e-6)) + aff ; per-group row max
  #pragma unroll
  for (int c = 0; c < GRP; ++c) {
    ushort4 av = *(const ushort4*)(aff + ((long)c << 20) + (n << 10) + m0);
    float l0 = __logf(fmaxf(acc[c][0], 1e-6f)) + bf2f(av.x);
    float l1 = __logf(fmaxf(acc[c][1], 1e-6f)) + bf2f(av.y);
    float l2 = __logf(fmaxf(acc[c][2], 1e-6f)) + bf2f(av.z);
    float l3 = __logf(fmaxf(acc[c][3], 1e-6f)) + bf2f(av.w);
    acc[c][0] = l0; acc[c][1] = l1; acc[c][2] = l2; acc[c][3] = l3;
    float v = fmaxf(fmaxf(l0, l1), fmaxf(l2, l3));
    #pragma unroll
    for (int off = 32; off; off >>= 1) v = fmaxf(v, __shfl_xor(v, off));
    if (lane == 0) red[c][wave] = v;
  }
  __syncthreads();
  float M[GRP];
  #pragma unroll
  for (int c = 0; c < GRP; ++c)
    M[c] = fmaxf(fmaxf(red[c][0], red[c][1]), fmaxf(red[c][2], red[c][3]));
  __syncthreads();

  #pragma unroll
  for (int c = 0; c < GRP; ++c) {
    float s = 0.f;
    #pragma unroll
    for (int jj = 0; jj < 4; ++jj) {
      float p = __expf(acc[c][jj] - M[c]);
      acc[c][jj] = p;
      s += p;
    }
    #pragma unroll
    for (int off = 32; off; off >>= 1) s += __shfl_xor(s, off);
    if (lane == 0) red[c][wave] = s;
  }
  __syncthreads();
  #pragma unroll
  for (int c = 0; c < GRP; ++c) {
    float s = red[c][0] + red[c][1] + red[c][2] + red[c][3];
    float r = 1.0f / s;
    ushort4 o;
    o.x = f2bf(acc[c][0] * r); o.y = f2bf(acc[c][1] * r);
    o.z = f2bf(acc[c][2] * r); o.w = f2bf(acc[c][3] * r);
    *(ushort4*)(S + (n << 14) + ((long)c << 10) + m0) = o;
  }
}

// ---------------------------------------------------------------------------
extern "C" void kernel_launch(void* const* d_in, const int* in_sizes, int n_in,
                              void* d_out, int out_size, void* d_ws, size_t ws_size,
                              hipStream_t stream)
{
  const float* roi   = (const float*)d_in[0];
  const float* pe    = (const float*)d_in[1];
  // d_in[2] = nongt_dim (always 1024 here)
  const float* pos_w = (const float*)d_in[3];
  const float* pos_b = (const float*)d_in[4];
  const float* q_w   = (const float*)d_in[5];
  const float* q_b   = (const float*)d_in[6];
  const float* k_w   = (const float*)d_in[7];
  const float* k_b   = (const float*)d_in[8];
  const float* out_w = (const float*)d_in[9];
  const float* out_b = (const float*)d_in[10];
  float* out = (float*)d_out;

  u16* roi_bf  = (u16*)d_ws;                 // [1024][1024]
  u16* roiT_bf = roi_bf  + (1 << 20);        // [1024][1024] (f,m)
  u16* qw_bf   = roiT_bf + (1 << 20);
  u16* kw_bf   = qw_bf   + (1 << 20);
  u16* ow_bf   = kw_bf   + (1 << 20);
  u16* q_bf    = ow_bf   + (1 << 20);        // [n][1024], pre-scaled 1/8
  u16* k_bf    = q_bf    + (1 << 20);
  u16* aff_bf  = k_bf    + (1 << 20);        // [16][1024][1024]
  u16* S_bf    = aff_bf  + (16 << 20);       // [1024][16][1024]
  u16* T_bf    = aff_bf;                     // aliases aff (dead after softmax)

  cvt_kernel<<<4096, 256, 0, stream>>>(roi, q_w, k_w, out_w,
                                       roi_bf, qw_bf, kw_bf, ow_bf);
  transpose_kernel<<<dim3(16, 16), 256, 0, stream>>>(roi, roiT_bf);

  // q = (roi @ q_w^T + q_b) / 8 ; k = roi @ k_w^T + k_b   (bf16 out)
  gemm_kernel<64, 64><<<dim3(16, 16, 1), 256, 0, stream>>>(
      roi_bf, FEAT, 0, qw_bf, FEAT, 0, q_bf, FEAT, 0, 1, q_b, 0, 0.125f, FEAT);
  gemm_kernel<64, 64><<<dim3(16, 16, 1), 256, 0, stream>>>(
      roi_bf, FEAT, 0, kw_bf, FEAT, 0, k_bf, FEAT, 0, 1, k_b, 0, 1.0f, FEAT);

  aff_kernel<<<dim3(16, 16, 16), 256, 0, stream>>>(q_bf, k_bf, aff_bf);

  softmax_kernel<<<1024, 256, 0, stream>>>(pe, pos_w, pos_b, aff_bf, S_bf);

  // T = S @ roi  (16384 x 1024 x 1024), bf16 out  (T aliases aff: safe, stream-ordered)
  gemm_kernel<128, 128><<<dim3(128, 8, 1), 256, 0, stream>>>(
      S_bf, FEAT, 0, roiT_bf, N_ROIS, 0, T_bf, FEAT, 0, 1, nullptr, 0, 1.0f, N_ROIS);

  // out[n][g*64+o] = sum_f T[n][g][f]*out_w[g*64+o][f] + out_b  (f32 out)
  gemm_kernel<64, 64><<<dim3(16, 1, 16), 256, 0, stream>>>(
      T_bf, (long)GRP * FEAT, (long)FEAT,
      ow_bf, FEAT, (long)DG * FEAT,
      out, FEAT, (long)DG, 0,
      out_b, (long)DG, 1.0f, FEAT);
}

// Round 3
// 492.318 us; speedup vs baseline: 1.1257x; 1.1257x over previous
//
#include <hip/hip_runtime.h>

#define N_ROIS 1024
#define FEAT   1024
#define GRP    16
#define DG     64
#define EMB    64

typedef __attribute__((ext_vector_type(8))) short short8;   // 8 bf16 = 4 VGPR (MFMA A/B frag)
typedef __attribute__((ext_vector_type(4))) float f32x4;    // MFMA C/D frag
typedef unsigned short u16;
typedef unsigned int   u32;

__device__ __forceinline__ u16 f2bf(float x) {              // RNE f32->bf16
  u32 u = __float_as_uint(x);
  u = (u + 0x7fff + ((u >> 16) & 1)) >> 16;
  return (u16)u;
}
__device__ __forceinline__ float bf2f(u16 h) {
  return __uint_as_float(((u32)h) << 16);
}

// async global->LDS, 16B per lane. LDS dest is wave-uniform base (+lane*16 in HW).
__device__ __forceinline__ void gload_lds16(const void* g, void* l) {
  __builtin_amdgcn_global_load_lds(
      (__attribute__((address_space(1))) const u32*)g,
      (__attribute__((address_space(3))) u32*)l, 16, 0, 0);
}

// ---------------- K0: f32 -> bf16 for roi, q_w, k_w, out_w; + bias gather --
__global__ __launch_bounds__(256) void cvt_kernel(
    const float* __restrict__ s0, const float* __restrict__ s1,
    const float* __restrict__ s2, const float* __restrict__ s3,
    u16* __restrict__ d0, u16* __restrict__ d1,
    u16* __restrict__ d2, u16* __restrict__ d3,
    const float* __restrict__ qb, const float* __restrict__ kb,
    float* __restrict__ qkb)
{
  if (blockIdx.x == 4096) {                         // bias gather: [q_b; k_b]
    int t = threadIdx.x;
    #pragma unroll
    for (int i = 0; i < 4; ++i) {
      qkb[t * 4 + i]        = qb[t * 4 + i];
      qkb[2048 + t * 4 + i] = kb[t * 4 + i];        // wait: 1024 each
    }
    return;
  }
  long id = (long)blockIdx.x * 256 + threadIdx.x;   // 1M float4 units total
  int seg = (int)(id >> 18);                        // 256K units per array
  long off = (id & 0x3ffff) * 4;
  const float* s = seg == 0 ? s0 : seg == 1 ? s1 : seg == 2 ? s2 : s3;
  u16* d       = seg == 0 ? d0 : seg == 1 ? d1 : seg == 2 ? d2 : d3;
  float4 v = *(const float4*)(s + off);
  ushort4 o;
  o.x = f2bf(v.x); o.y = f2bf(v.y); o.z = f2bf(v.z); o.w = f2bf(v.w);
  *(ushort4*)(d + off) = o;
}

// ---------------- generic bf16 MFMA GEMM: C = (A * B^T + bias) * scale -----
// A: MxK row-major (lda), B: NxK row-major (ldb), both bf16; z-batched via
// Az/Bz/Cz/biasz element strides. 256 thr = 4 waves in 2x2; 16x16x32 MFMA.
// LDS rows 128B, XOR swizzle chunk ^= (row&7): linear global_load_lds dest +
// pre-swizzled source + swizzled read (both-sides rule; frag row&7 == lane&7).
template<int BM, int BN>
__global__ __launch_bounds__(256) void gemm_kernel(
    const u16* __restrict__ A, long lda, long Az,
    const u16* __restrict__ B, long ldb, long Bz,
    void* __restrict__ Cv, long ldc, long Cz, int c_bf16,
    const float* __restrict__ bias, long biasz,
    float scale, int K)
{
  constexpr int BK = 64;
  constexpr int WM = BM / 2, WN = BN / 2;
  constexpr int FM = WM / 16, FN = WN / 16;
  __shared__ u16 lA[BM * BK];
  __shared__ u16 lB[BN * BK];
  const int t = threadIdx.x;
  const int lane = t & 63;
  const int wave = t >> 6;
  const int wr = wave >> 1, wc = wave & 1;
  const long m0 = (long)blockIdx.x * BM;
  const long n0 = (long)blockIdx.y * BN;
  const int z = blockIdx.z;
  const u16* Ab = A + z * Az + m0 * lda;
  const u16* Bb = B + z * Bz + n0 * ldb;

  f32x4 acc[FM][FN];
  #pragma unroll
  for (int i = 0; i < FM; ++i)
    #pragma unroll
    for (int j = 0; j < FN; ++j)
      acc[i][j] = (f32x4){0.f, 0.f, 0.f, 0.f};

  for (int kk = 0; kk < K; kk += BK) {
    __syncthreads();
    #pragma unroll
    for (int qq = 0; qq < BM / 32; ++qq) {          // stage A (4KB per issue)
      int off = qq * 4096 + t * 16;
      int row = off >> 7;                           // 128B rows
      int sc = (t & 7) ^ (row & 7);                 // pre-swizzled source chunk
      gload_lds16(Ab + (long)row * lda + kk + sc * 8,
                  (char*)lA + qq * 4096 + (t & ~63) * 16);
    }
    #pragma unroll
    for (int qq = 0; qq < BN / 32; ++qq) {          // stage B
      int off = qq * 4096 + t * 16;
      int row = off >> 7;
      int sc = (t & 7) ^ (row & 7);
      gload_lds16(Bb + (long)row * ldb + kk + sc * 8,
                  (char*)lB + qq * 4096 + (t & ~63) * 16);
    }
    __syncthreads();                                // drains vmcnt before use
    #pragma unroll
    for (int ks = 0; ks < 2; ++ks) {                // two K=32 steps
      short8 af[FM], bfr[FN];
      #pragma unroll
      for (int i = 0; i < FM; ++i) {
        int row = wr * WM + i * 16 + (lane & 15);
        int sc = (ks * 4 + (lane >> 4)) ^ (lane & 7);
        af[i] = *(const short8*)((const char*)lA + row * 128 + sc * 16);
      }
      #pragma unroll
      for (int j = 0; j < FN; ++j) {
        int row = wc * WN + j * 16 + (lane & 15);
        int sc = (ks * 4 + (lane >> 4)) ^ (lane & 7);
        bfr[j] = *(const short8*)((const char*)lB + row * 128 + sc * 16);
      }
      #pragma unroll
      for (int i = 0; i < FM; ++i)
        #pragma unroll
        for (int j = 0; j < FN; ++j)
          acc[i][j] = __builtin_amdgcn_mfma_f32_16x16x32_bf16(af[i], bfr[j], acc[i][j], 0, 0, 0);
    }
  }

  const float* bz = bias ? bias + z * biasz : nullptr;
  #pragma unroll
  for (int i = 0; i < FM; ++i) {
    #pragma unroll
    for (int j = 0; j < FN; ++j) {
      long col = n0 + wc * WN + j * 16 + (lane & 15);
      float b = bz ? bz[col] : 0.f;
      #pragma unroll
      for (int r = 0; r < 4; ++r) {                 // D: row=(l>>4)*4+r, col=l&15
        long row = m0 + wr * WM + i * 16 + (lane >> 4) * 4 + r;
        float v = (acc[i][j][r] + b) * scale;
        long idx = row * ldc + col + (long)z * Cz;
        if (c_bf16) ((u16*)Cv)[idx] = f2bf(v);
        else        ((float*)Cv)[idx] = v;
      }
    }
  }
}

// ---------------- aff[g][n][m] = 0.125 * sum_d q[n][g*64+d] * k[m][g*64+d] -
// K=64 -> 2 MFMAs; frags loaded directly (q,k are L2-hot).
__global__ __launch_bounds__(256) void aff_kernel(
    const u16* __restrict__ q, const u16* __restrict__ k, u16* __restrict__ aff)
{
  const int t = threadIdx.x;
  const int lane = t & 63;
  const int wave = t >> 6;
  const int g = blockIdx.z;
  const long n0 = (long)blockIdx.x * 64 + wave * 16;
  const long m0 = (long)blockIdx.y * 64;
  const u16* qp = q + (n0 + (lane & 15)) * (GRP * DG) + g * DG + (lane >> 4) * 8;
  short8 a0 = *(const short8*)qp;
  short8 a1 = *(const short8*)(qp + 32);
  f32x4 acc[4];
  #pragma unroll
  for (int mt = 0; mt < 4; ++mt) acc[mt] = (f32x4){0.f, 0.f, 0.f, 0.f};
  #pragma unroll
  for (int mt = 0; mt < 4; ++mt) {
    const u16* kp = k + (m0 + mt * 16 + (lane & 15)) * (GRP * DG) + g * DG + (lane >> 4) * 8;
    short8 b0 = *(const short8*)kp;
    short8 b1 = *(const short8*)(kp + 32);
    acc[mt] = __builtin_amdgcn_mfma_f32_16x16x32_bf16(a0, b0, acc[mt], 0, 0, 0);
    acc[mt] = __builtin_amdgcn_mfma_f32_16x16x32_bf16(a1, b1, acc[mt], 0, 0, 0);
  }
  #pragma unroll
  for (int mt = 0; mt < 4; ++mt)
    #pragma unroll
    for (int r = 0; r < 4; ++r) {
      long n = n0 + (lane >> 4) * 4 + r;
      long m = m0 + mt * 16 + (lane & 15);
      aff[((long)g << 20) + (n << 10) + m] = f2bf(acc[mt][r] * 0.125f);
    }
}

// ---------------- pf + relu + log + aff -> softmax -> S (bf16) -------------
// One block per n. pe is read exactly once across the grid (268MB = the floor).
// Thread t owns m in [4t,4t+4) for ALL 16 groups; softmax reduced via shfl+LDS.
__global__ __launch_bounds__(256) void softmax_kernel(
    const float* __restrict__ pe, const float* __restrict__ pos_w,
    const float* __restrict__ pos_b, const u16* __restrict__ aff,
    u16* __restrict__ S)
{
  __shared__ float pw[GRP * EMB];
  __shared__ float red[GRP][4];
  const int t = threadIdx.x;
  const int lane = t & 63;
  const int wave = t >> 6;
  const long n = blockIdx.x;
  const int m0 = t * 4;

  for (int i = t; i < GRP * EMB; i += 256) pw[i] = pos_w[i];

  float acc[GRP][4];
  #pragma unroll
  for (int c = 0; c < GRP; ++c) {
    float b = pos_b[c];
    acc[c][0] = b; acc[c][1] = b; acc[c][2] = b; acc[c][3] = b;
  }
  __syncthreads();

  for (int e = 0; e < EMB; ++e) {
    float4 pv = *(const float4*)(pe + ((long)e * N_ROIS + n) * N_ROIS + m0);
    #pragma unroll
    for (int c = 0; c < GRP; ++c) {
      float w = pw[c * EMB + e];                    // broadcast, conflict-free
      acc[c][0] = fmaf(w, pv.x, acc[c][0]);
      acc[c][1] = fmaf(w, pv.y, acc[c][1]);
      acc[c][2] = fmaf(w, pv.z, acc[c][2]);
      acc[c][3] = fmaf(w, pv.w, acc[c][3]);
    }
  }

  // logits = log(max(relu(pf),1e-6)) + aff ; per-group row max
  #pragma unroll
  for (int c = 0; c < GRP; ++c) {
    ushort4 av = *(const ushort4*)(aff + ((long)c << 20) + (n << 10) + m0);
    float l0 = __logf(fmaxf(acc[c][0], 1e-6f)) + bf2f(av.x);
    float l1 = __logf(fmaxf(acc[c][1], 1e-6f)) + bf2f(av.y);
    float l2 = __logf(fmaxf(acc[c][2], 1e-6f)) + bf2f(av.z);
    float l3 = __logf(fmaxf(acc[c][3], 1e-6f)) + bf2f(av.w);
    acc[c][0] = l0; acc[c][1] = l1; acc[c][2] = l2; acc[c][3] = l3;
    float v = fmaxf(fmaxf(l0, l1), fmaxf(l2, l3));
    #pragma unroll
    for (int off = 32; off; off >>= 1) v = fmaxf(v, __shfl_xor(v, off));
    if (lane == 0) red[c][wave] = v;
  }
  __syncthreads();
  float M[GRP];
  #pragma unroll
  for (int c = 0; c < GRP; ++c)
    M[c] = fmaxf(fmaxf(red[c][0], red[c][1]), fmaxf(red[c][2], red[c][3]));
  __syncthreads();

  #pragma unroll
  for (int c = 0; c < GRP; ++c) {
    float s = 0.f;
    #pragma unroll
    for (int jj = 0; jj < 4; ++jj) {
      float p = __expf(acc[c][jj] - M[c]);
      acc[c][jj] = p;
      s += p;
    }
    #pragma unroll
    for (int off = 32; off; off >>= 1) s += __shfl_xor(s, off);
    if (lane == 0) red[c][wave] = s;
  }
  __syncthreads();
  #pragma unroll
  for (int c = 0; c < GRP; ++c) {
    float s = red[c][0] + red[c][1] + red[c][2] + red[c][3];
    float r = 1.0f / s;
    ushort4 o;
    o.x = f2bf(acc[c][0] * r); o.y = f2bf(acc[c][1] * r);
    o.z = f2bf(acc[c][2] * r); o.w = f2bf(acc[c][3] * r);
    *(ushort4*)(S + (n << 14) + ((long)c << 10) + m0) = o;
  }
}

// ---------------------------------------------------------------------------
extern "C" void kernel_launch(void* const* d_in, const int* in_sizes, int n_in,
                              void* d_out, int out_size, void* d_ws, size_t ws_size,
                              hipStream_t stream)
{
  const float* roi   = (const float*)d_in[0];
  const float* pe    = (const float*)d_in[1];
  // d_in[2] = nongt_dim (always 1024 here)
  const float* pos_w = (const float*)d_in[3];
  const float* pos_b = (const float*)d_in[4];
  const float* q_w   = (const float*)d_in[5];
  const float* q_b   = (const float*)d_in[6];
  const float* k_w   = (const float*)d_in[7];
  const float* k_b   = (const float*)d_in[8];
  const float* out_w = (const float*)d_in[9];
  const float* out_b = (const float*)d_in[10];
  float* out = (float*)d_out;

  const long M1 = 1l << 20;
  u16* roi_bf = (u16*)d_ws;                  // [1024][1024]
  u16* qw_bf  = roi_bf + M1;                 // [1024][1024]  (qw,kw adjacent)
  u16* kw_bf  = qw_bf  + M1;
  u16* ow_bf  = kw_bf  + M1;
  u16* q_bf   = ow_bf  + M1;                 // [n][1024]     (q,k adjacent)
  u16* k_bf   = q_bf   + M1;
  u16* aff_bf = k_bf   + M1;                 // [16][1024][1024]
  u16* S_bf   = aff_bf + 16 * M1;            // [1024][16][1024]
  u16* W2T    = S_bf   + 16 * M1;            // [16][64][1024]
  float* qkb  = (float*)(W2T + M1);          // [2048] = [q_b; k_b]

  cvt_kernel<<<4097, 256, 0, stream>>>(roi, q_w, k_w, out_w,
                                       roi_bf, qw_bf, kw_bf, ow_bf,
                                       q_b, k_b, qkb);

  // W2T[g][o][m] = sum_f out_w[g*64+o][f] * roi[m][f]   (2.1 GF, bf16 out)
  gemm_kernel<64, 64><<<dim3(1, 16, 16), 256, 0, stream>>>(
      ow_bf, FEAT, (long)DG * FEAT,
      roi_bf, FEAT, 0,
      W2T, N_ROIS, (long)DG * N_ROIS, 1,
      nullptr, 0, 1.0f, FEAT);

  // q = roi @ q_w^T + q_b ; k = roi @ k_w^T + k_b   (z=2 batched, bf16 out)
  gemm_kernel<64, 64><<<dim3(16, 16, 2), 256, 0, stream>>>(
      roi_bf, FEAT, 0,
      qw_bf, FEAT, M1,
      q_bf, FEAT, M1, 1,
      qkb, N_ROIS, 1.0f, FEAT);

  aff_kernel<<<dim3(16, 16, 16), 256, 0, stream>>>(q_bf, k_bf, aff_bf);

  softmax_kernel<<<1024, 256, 0, stream>>>(pe, pos_w, pos_b, aff_bf, S_bf);

  // out[n][g*64+o] = sum_m S[n*16+g][m] * W2T[g][o][m] + out_b  (f32 out)
  gemm_kernel<64, 64><<<dim3(16, 1, 16), 256, 0, stream>>>(
      S_bf, (long)GRP * N_ROIS, (long)N_ROIS,
      W2T, N_ROIS, (long)DG * N_ROIS,
      out, FEAT, (long)DG, 0,
      out_b, (long)DG, 1.0f, FEAT);
}

// Round 4
// 481.663 us; speedup vs baseline: 1.1506x; 1.0221x over previous
//
#include <hip/hip_runtime.h>

#define N_ROIS 1024
#define FEAT   1024
#define GRP    16
#define DG     64
#define EMB    64

typedef __attribute__((ext_vector_type(8))) short short8;   // 8 bf16 = 4 VGPR (MFMA A/B frag)
typedef __attribute__((ext_vector_type(4))) float f32x4;    // MFMA C/D frag
typedef unsigned short u16;
typedef unsigned int   u32;

__device__ __forceinline__ u16 f2bf(float x) {              // RNE f32->bf16
  u32 u = __float_as_uint(x);
  u = (u + 0x7fff + ((u >> 16) & 1)) >> 16;
  return (u16)u;
}
__device__ __forceinline__ float bf2f(u16 h) {
  return __uint_as_float(((u32)h) << 16);
}

// async global->LDS, 16B per lane. LDS dest is wave-uniform base (+lane*16 in HW).
__device__ __forceinline__ void gload_lds16(const void* g, void* l) {
  __builtin_amdgcn_global_load_lds(
      (__attribute__((address_space(1))) const u32*)g,
      (__attribute__((address_space(3))) u32*)l, 16, 0, 0);
}

// ---------------- K0: f32 -> bf16 for roi, q_w, k_w, out_w; + bias gather --
__global__ __launch_bounds__(256) void cvt_kernel(
    const float* __restrict__ s0, const float* __restrict__ s1,
    const float* __restrict__ s2, const float* __restrict__ s3,
    u16* __restrict__ d0, u16* __restrict__ d1,
    u16* __restrict__ d2, u16* __restrict__ d3,
    const float* __restrict__ qb, const float* __restrict__ kb,
    float* __restrict__ qkb)
{
  if (blockIdx.x == 4096) {                         // bias gather: [q_b; k_b]
    int t = threadIdx.x;
    #pragma unroll
    for (int i = 0; i < 4; ++i) {
      qkb[t * 4 + i]        = qb[t * 4 + i];        // [0,1024)   = q_b
      qkb[1024 + t * 4 + i] = kb[t * 4 + i];        // [1024,2048)= k_b
    }
    return;
  }
  long id = (long)blockIdx.x * 256 + threadIdx.x;   // 1M float4 units total
  int seg = (int)(id >> 18);                        // 256K units per array
  long off = (id & 0x3ffff) * 4;
  const float* s = seg == 0 ? s0 : seg == 1 ? s1 : seg == 2 ? s2 : s3;
  u16* d       = seg == 0 ? d0 : seg == 1 ? d1 : seg == 2 ? d2 : d3;
  float4 v = *(const float4*)(s + off);
  ushort4 o;
  o.x = f2bf(v.x); o.y = f2bf(v.y); o.z = f2bf(v.z); o.w = f2bf(v.w);
  *(ushort4*)(d + off) = o;
}

// ---------------- shared bf16 MFMA GEMM body: C = (A * B^T + bias) * scale -
// A: MxK row-major (lda), B: NxK row-major (ldb), both bf16. 256 thr =
// 4 waves 2x2; 16x16x32 MFMA. LDS rows 128B, XOR swizzle chunk ^= (row&7):
// linear global_load_lds dest + pre-swizzled source + swizzled read
// (both-sides rule; frag row&7 == lane&7). Ab/Bb/bias pre-z-offset by caller;
// m0/n0 from blockIdx; C index = row*ldc + col + coff.
template<int BM, int BN>
__device__ __forceinline__ void gemm_body(
    const u16* __restrict__ Ab, long lda,
    const u16* __restrict__ Bb, long ldb,
    void* __restrict__ Cv, long ldc, long coff, int c_bf16,
    const float* __restrict__ bias, float scale, int K)
{
  constexpr int BK = 64;
  constexpr int WM = BM / 2, WN = BN / 2;
  constexpr int FM = WM / 16, FN = WN / 16;
  __shared__ u16 lA[BM * BK];
  __shared__ u16 lB[BN * BK];
  const int t = threadIdx.x;
  const int lane = t & 63;
  const int wave = t >> 6;
  const int wr = wave >> 1, wc = wave & 1;
  const long m0 = (long)blockIdx.x * BM;
  const long n0 = (long)blockIdx.y * BN;
  const u16* Ap = Ab + m0 * lda;
  const u16* Bp = Bb + n0 * ldb;

  f32x4 acc[FM][FN];
  #pragma unroll
  for (int i = 0; i < FM; ++i)
    #pragma unroll
    for (int j = 0; j < FN; ++j)
      acc[i][j] = (f32x4){0.f, 0.f, 0.f, 0.f};

  for (int kk = 0; kk < K; kk += BK) {
    __syncthreads();
    #pragma unroll
    for (int qq = 0; qq < BM / 32; ++qq) {          // stage A (4KB per issue)
      int off = qq * 4096 + t * 16;
      int row = off >> 7;                           // 128B rows
      int sc = (t & 7) ^ (row & 7);                 // pre-swizzled source chunk
      gload_lds16(Ap + (long)row * lda + kk + sc * 8,
                  (char*)lA + qq * 4096 + (t & ~63) * 16);
    }
    #pragma unroll
    for (int qq = 0; qq < BN / 32; ++qq) {          // stage B
      int off = qq * 4096 + t * 16;
      int row = off >> 7;
      int sc = (t & 7) ^ (row & 7);
      gload_lds16(Bp + (long)row * ldb + kk + sc * 8,
                  (char*)lB + qq * 4096 + (t & ~63) * 16);
    }
    __syncthreads();                                // drains vmcnt before use
    #pragma unroll
    for (int ks = 0; ks < 2; ++ks) {                // two K=32 steps
      short8 af[FM], bfr[FN];
      #pragma unroll
      for (int i = 0; i < FM; ++i) {
        int row = wr * WM + i * 16 + (lane & 15);
        int sc = (ks * 4 + (lane >> 4)) ^ (lane & 7);
        af[i] = *(const short8*)((const char*)lA + row * 128 + sc * 16);
      }
      #pragma unroll
      for (int j = 0; j < FN; ++j) {
        int row = wc * WN + j * 16 + (lane & 15);
        int sc = (ks * 4 + (lane >> 4)) ^ (lane & 7);
        bfr[j] = *(const short8*)((const char*)lB + row * 128 + sc * 16);
      }
      #pragma unroll
      for (int i = 0; i < FM; ++i)
        #pragma unroll
        for (int j = 0; j < FN; ++j)
          acc[i][j] = __builtin_amdgcn_mfma_f32_16x16x32_bf16(af[i], bfr[j], acc[i][j], 0, 0, 0);
    }
  }

  #pragma unroll
  for (int i = 0; i < FM; ++i) {
    #pragma unroll
    for (int j = 0; j < FN; ++j) {
      long col = n0 + wc * WN + j * 16 + (lane & 15);
      float b = bias ? bias[col] : 0.f;
      #pragma unroll
      for (int r = 0; r < 4; ++r) {                 // D: row=(l>>4)*4+r, col=l&15
        long row = m0 + wr * WM + i * 16 + (lane >> 4) * 4 + r;
        float v = (acc[i][j][r] + b) * scale;
        long idx = row * ldc + col + coff;
        if (c_bf16) ((u16*)Cv)[idx] = f2bf(v);
        else        ((float*)Cv)[idx] = v;
      }
    }
  }
}

// generic z-batched wrapper
template<int BM, int BN>
__global__ __launch_bounds__(256) void gemm_kernel(
    const u16* __restrict__ A, long lda, long Az,
    const u16* __restrict__ B, long ldb, long Bz,
    void* __restrict__ Cv, long ldc, long Cz, int c_bf16,
    const float* __restrict__ bias, long biasz,
    float scale, int K)
{
  const int z = blockIdx.z;
  gemm_body<BM, BN>(A + z * Az, lda, B + z * Bz, ldb,
                    Cv, ldc, (long)z * Cz, c_bf16,
                    bias ? bias + z * biasz : nullptr, scale, K);
}

// fused launch: z=0 -> q, z=1 -> k, z=2 -> W2T_flat (all 1024x1024, K=1024)
__global__ __launch_bounds__(256) void gemm3_kernel(
    const u16* __restrict__ roi, const u16* __restrict__ qw,
    const u16* __restrict__ kw, const u16* __restrict__ ow,
    u16* __restrict__ q, u16* __restrict__ k, u16* __restrict__ w2t,
    const float* __restrict__ qkb)
{
  const int z = blockIdx.z;
  const u16* A = z == 2 ? ow : roi;
  const u16* B = z == 0 ? qw : z == 1 ? kw : roi;
  u16* C       = z == 0 ? q  : z == 1 ? k  : w2t;
  const float* bias = z == 0 ? qkb : z == 1 ? qkb + 1024 : nullptr;
  gemm_body<64, 64>(A, FEAT, B, FEAT, C, FEAT, 0, 1, bias, 1.0f, FEAT);
}

// ---------------- aff[g][n][m] = 0.125 * sum_d q[n][g*64+d] * k[m][g*64+d] -
// K=64 -> 2 MFMAs; frags loaded directly (q,k are L2-hot).
__global__ __launch_bounds__(256) void aff_kernel(
    const u16* __restrict__ q, const u16* __restrict__ k, u16* __restrict__ aff)
{
  const int t = threadIdx.x;
  const int lane = t & 63;
  const int wave = t >> 6;
  const int g = blockIdx.z;
  const long n0 = (long)blockIdx.x * 64 + wave * 16;
  const long m0 = (long)blockIdx.y * 64;
  const u16* qp = q + (n0 + (lane & 15)) * (GRP * DG) + g * DG + (lane >> 4) * 8;
  short8 a0 = *(const short8*)qp;
  short8 a1 = *(const short8*)(qp + 32);
  f32x4 acc[4];
  #pragma unroll
  for (int mt = 0; mt < 4; ++mt) acc[mt] = (f32x4){0.f, 0.f, 0.f, 0.f};
  #pragma unroll
  for (int mt = 0; mt < 4; ++mt) {
    const u16* kp = k + (m0 + mt * 16 + (lane & 15)) * (GRP * DG) + g * DG + (lane >> 4) * 8;
    short8 b0 = *(const short8*)kp;
    short8 b1 = *(const short8*)(kp + 32);
    acc[mt] = __builtin_amdgcn_mfma_f32_16x16x32_bf16(a0, b0, acc[mt], 0, 0, 0);
    acc[mt] = __builtin_amdgcn_mfma_f32_16x16x32_bf16(a1, b1, acc[mt], 0, 0, 0);
  }
  #pragma unroll
  for (int mt = 0; mt < 4; ++mt)
    #pragma unroll
    for (int r = 0; r < 4; ++r) {
      long n = n0 + (lane >> 4) * 4 + r;
      long m = m0 + mt * 16 + (lane & 15);
      aff[((long)g << 20) + (n << 10) + m] = f2bf(acc[mt][r] * 0.125f);
    }
}

// ---------------- pf + relu + log + aff -> softmax -> S (bf16) -------------
// One block per n. pe is read exactly once across the grid (268MB = the floor).
// Thread t owns m in [4t,4t+4) for ALL 16 groups; softmax reduced via shfl+LDS.
__global__ __launch_bounds__(256) void softmax_kernel(
    const float* __restrict__ pe, const float* __restrict__ pos_w,
    const float* __restrict__ pos_b, const u16* __restrict__ aff,
    u16* __restrict__ S)
{
  __shared__ float pw[GRP * EMB];
  __shared__ float red[GRP][4];
  const int t = threadIdx.x;
  const int lane = t & 63;
  const int wave = t >> 6;
  const long n = blockIdx.x;
  const int m0 = t * 4;

  for (int i = t; i < GRP * EMB; i += 256) pw[i] = pos_w[i];

  float acc[GRP][4];
  #pragma unroll
  for (int c = 0; c < GRP; ++c) {
    float b = pos_b[c];
    acc[c][0] = b; acc[c][1] = b; acc[c][2] = b; acc[c][3] = b;
  }
  __syncthreads();

  const float* per = pe + n * N_ROIS + m0;
  #pragma unroll 2
  for (int e = 0; e < EMB; ++e) {
    float4 pv = *(const float4*)(per + (long)e * N_ROIS * N_ROIS);
    #pragma unroll
    for (int c = 0; c < GRP; ++c) {
      float w = pw[c * EMB + e];                    // broadcast, conflict-free
      acc[c][0] = fmaf(w, pv.x, acc[c][0]);
      acc[c][1] = fmaf(w, pv.y, acc[c][1]);
      acc[c][2] = fmaf(w, pv.z, acc[c][2]);
      acc[c][3] = fmaf(w, pv.w, acc[c][3]);
    }
  }

  // logits = log(max(relu(pf),1e-6)) + aff ; per-group row max
  #pragma unroll
  for (int c = 0; c < GRP; ++c) {
    ushort4 av = *(const ushort4*)(aff + ((long)c << 20) + (n << 10) + m0);
    float l0 = __logf(fmaxf(acc[c][0], 1e-6f)) + bf2f(av.x);
    float l1 = __logf(fmaxf(acc[c][1], 1e-6f)) + bf2f(av.y);
    float l2 = __logf(fmaxf(acc[c][2], 1e-6f)) + bf2f(av.z);
    float l3 = __logf(fmaxf(acc[c][3], 1e-6f)) + bf2f(av.w);
    acc[c][0] = l0; acc[c][1] = l1; acc[c][2] = l2; acc[c][3] = l3;
    float v = fmaxf(fmaxf(l0, l1), fmaxf(l2, l3));
    #pragma unroll
    for (int off = 32; off; off >>= 1) v = fmaxf(v, __shfl_xor(v, off));
    if (lane == 0) red[c][wave] = v;
  }
  __syncthreads();
  float M[GRP];
  #pragma unroll
  for (int c = 0; c < GRP; ++c)
    M[c] = fmaxf(fmaxf(red[c][0], red[c][1]), fmaxf(red[c][2], red[c][3]));
  __syncthreads();

  #pragma unroll
  for (int c = 0; c < GRP; ++c) {
    float s = 0.f;
    #pragma unroll
    for (int jj = 0; jj < 4; ++jj) {
      float p = __expf(acc[c][jj] - M[c]);
      acc[c][jj] = p;
      s += p;
    }
    #pragma unroll
    for (int off = 32; off; off >>= 1) s += __shfl_xor(s, off);
    if (lane == 0) red[c][wave] = s;
  }
  __syncthreads();
  #pragma unroll
  for (int c = 0; c < GRP; ++c) {
    float s = red[c][0] + red[c][1] + red[c][2] + red[c][3];
    float r = 1.0f / s;
    ushort4 o;
    o.x = f2bf(acc[c][0] * r); o.y = f2bf(acc[c][1] * r);
    o.z = f2bf(acc[c][2] * r); o.w = f2bf(acc[c][3] * r);
    *(ushort4*)(S + (n << 14) + ((long)c << 10) + m0) = o;
  }
}

// ---------------------------------------------------------------------------
extern "C" void kernel_launch(void* const* d_in, const int* in_sizes, int n_in,
                              void* d_out, int out_size, void* d_ws, size_t ws_size,
                              hipStream_t stream)
{
  const float* roi   = (const float*)d_in[0];
  const float* pe    = (const float*)d_in[1];
  // d_in[2] = nongt_dim (always 1024 here)
  const float* pos_w = (const float*)d_in[3];
  const float* pos_b = (const float*)d_in[4];
  const float* q_w   = (const float*)d_in[5];
  const float* q_b   = (const float*)d_in[6];
  const float* k_w   = (const float*)d_in[7];
  const float* k_b   = (const float*)d_in[8];
  const float* out_w = (const float*)d_in[9];
  const float* out_b = (const float*)d_in[10];
  float* out = (float*)d_out;

  const long M1 = 1l << 20;
  u16* roi_bf = (u16*)d_ws;                  // [1024][1024]
  u16* qw_bf  = roi_bf + M1;                 // [1024][1024]
  u16* kw_bf  = qw_bf  + M1;
  u16* ow_bf  = kw_bf  + M1;
  u16* q_bf   = ow_bf  + M1;                 // [n][1024]
  u16* k_bf   = q_bf   + M1;
  u16* aff_bf = k_bf   + M1;                 // [16][1024][1024]
  u16* S_bf   = aff_bf + 16 * M1;            // [1024][16][1024]
  u16* W2T    = S_bf   + 16 * M1;            // [16*64][1024] (flat go x m)
  float* qkb  = (float*)(W2T + M1);          // [2048] = [q_b; k_b]

  cvt_kernel<<<4097, 256, 0, stream>>>(roi, q_w, k_w, out_w,
                                       roi_bf, qw_bf, kw_bf, ow_bf,
                                       q_b, k_b, qkb);

  // one launch, 768 blocks: q = roi@qw^T+qb, k = roi@kw^T+kb,
  // W2T[g*64+o][m] = sum_f out_w[g*64+o][f]*roi[m][f]
  gemm3_kernel<<<dim3(16, 16, 3), 256, 0, stream>>>(
      roi_bf, qw_bf, kw_bf, ow_bf, q_bf, k_bf, W2T, qkb);

  aff_kernel<<<dim3(16, 16, 16), 256, 0, stream>>>(q_bf, k_bf, aff_bf);

  softmax_kernel<<<1024, 256, 0, stream>>>(pe, pos_w, pos_b, aff_bf, S_bf);

  // out[n][g*64+o] = sum_m S[n*16+g][m] * W2T[g*64+o][m] + out_b  (f32 out)
  gemm_kernel<64, 64><<<dim3(16, 1, 16), 256, 0, stream>>>(
      S_bf, (long)GRP * N_ROIS, (long)N_ROIS,
      W2T, N_ROIS, (long)DG * N_ROIS,
      out, FEAT, (long)DG, 0,
      out_b, (long)DG, 1.0f, FEAT);
}

// Round 5
// 476.680 us; speedup vs baseline: 1.1626x; 1.0105x over previous
//
#include <hip/hip_runtime.h>

#define N_ROIS 1024
#define FEAT   1024
#define GRP    16
#define DG     64
#define EMB    64

typedef __attribute__((ext_vector_type(8))) short short8;   // 8 bf16 = 4 VGPR (MFMA A/B frag)
typedef __attribute__((ext_vector_type(4))) float f32x4;    // MFMA C/D frag
typedef unsigned short u16;
typedef unsigned int   u32;

__device__ __forceinline__ u16 f2bf(float x) {              // RNE f32->bf16
  u32 u = __float_as_uint(x);
  u = (u + 0x7fff + ((u >> 16) & 1)) >> 16;
  return (u16)u;
}
__device__ __forceinline__ float bf2f(u16 h) {
  return __uint_as_float(((u32)h) << 16);
}

// async global->LDS, 16B per lane. LDS dest is wave-uniform base (+lane*16 in HW).
__device__ __forceinline__ void gload_lds16(const void* g, void* l) {
  __builtin_amdgcn_global_load_lds(
      (__attribute__((address_space(1))) const u32*)g,
      (__attribute__((address_space(3))) u32*)l, 16, 0, 0);
}

// ---- K0: f32->bf16 (roi,q_w,k_w,out_w) + bias gather + out bias-init ------
// blocks [0,4096): cvt; 4096: qkb gather; (4096,5120]: out[n][j] = out_b[j]
// (out init is REQUIRED every call: harness poisons d_out, final gemm atomicAdds).
__global__ __launch_bounds__(256) void cvt_kernel(
    const float* __restrict__ s0, const float* __restrict__ s1,
    const float* __restrict__ s2, const float* __restrict__ s3,
    u16* __restrict__ d0, u16* __restrict__ d1,
    u16* __restrict__ d2, u16* __restrict__ d3,
    const float* __restrict__ qb, const float* __restrict__ kb,
    float* __restrict__ qkb,
    const float* __restrict__ ob, float* __restrict__ out)
{
  const int t = threadIdx.x;
  if (blockIdx.x == 4096) {                         // bias gather: [q_b; k_b]
    #pragma unroll
    for (int i = 0; i < 4; ++i) {
      qkb[t * 4 + i]        = qb[t * 4 + i];        // [0,1024)   = q_b
      qkb[1024 + t * 4 + i] = kb[t * 4 + i];        // [1024,2048)= k_b
    }
    return;
  }
  if (blockIdx.x > 4096) {                          // out init with out_b
    long id = (long)(blockIdx.x - 4097) * 1024 + t * 4;   // 1M floats total
    float4 bv = *(const float4*)(ob + (id & 1023));
    *(float4*)(out + id) = bv;
    return;
  }
  long id = (long)blockIdx.x * 256 + t;             // 1M float4 units total
  int seg = (int)(id >> 18);                        // 256K units per array
  long off = (id & 0x3ffff) * 4;
  const float* s = seg == 0 ? s0 : seg == 1 ? s1 : seg == 2 ? s2 : s3;
  u16* d       = seg == 0 ? d0 : seg == 1 ? d1 : seg == 2 ? d2 : d3;
  float4 v = *(const float4*)(s + off);
  ushort4 o;
  o.x = f2bf(v.x); o.y = f2bf(v.y); o.z = f2bf(v.z); o.w = f2bf(v.w);
  *(ushort4*)(d + off) = o;
}

// ---------------- shared bf16 MFMA GEMM body: C = (A * B^T + bias) * scale -
// A: MxK row-major (lda), B: NxK row-major (ldb), both bf16. 256 thr =
// 4 waves 2x2; 16x16x32 MFMA. LDS rows 128B, XOR swizzle chunk ^= (row&7):
// linear global_load_lds dest + pre-swizzled source + swizzled read
// (both-sides rule; frag row&7 == lane&7). Ab/Bb/bias pre-offset by caller;
// m0/n0 from blockIdx.x/y; C index = row*ldc + col + coff.
// mode: 0 = f32 store, 1 = bf16 store, 2 = f32 atomicAdd (K-split partials).
template<int BM, int BN>
__device__ __forceinline__ void gemm_body(
    const u16* __restrict__ Ab, long lda,
    const u16* __restrict__ Bb, long ldb,
    void* __restrict__ Cv, long ldc, long coff, int mode,
    const float* __restrict__ bias, float scale, int K)
{
  constexpr int BK = 64;
  constexpr int WM = BM / 2, WN = BN / 2;
  constexpr int FM = WM / 16, FN = WN / 16;
  __shared__ u16 lA[BM * BK];
  __shared__ u16 lB[BN * BK];
  const int t = threadIdx.x;
  const int lane = t & 63;
  const int wave = t >> 6;
  const int wr = wave >> 1, wc = wave & 1;
  const long m0 = (long)blockIdx.x * BM;
  const long n0 = (long)blockIdx.y * BN;
  const u16* Ap = Ab + m0 * lda;
  const u16* Bp = Bb + n0 * ldb;

  f32x4 acc[FM][FN];
  #pragma unroll
  for (int i = 0; i < FM; ++i)
    #pragma unroll
    for (int j = 0; j < FN; ++j)
      acc[i][j] = (f32x4){0.f, 0.f, 0.f, 0.f};

  for (int kk = 0; kk < K; kk += BK) {
    __syncthreads();
    #pragma unroll
    for (int qq = 0; qq < BM / 32; ++qq) {          // stage A (4KB per issue)
      int off = qq * 4096 + t * 16;
      int row = off >> 7;                           // 128B rows
      int sc = (t & 7) ^ (row & 7);                 // pre-swizzled source chunk
      gload_lds16(Ap + (long)row * lda + kk + sc * 8,
                  (char*)lA + qq * 4096 + (t & ~63) * 16);
    }
    #pragma unroll
    for (int qq = 0; qq < BN / 32; ++qq) {          // stage B
      int off = qq * 4096 + t * 16;
      int row = off >> 7;
      int sc = (t & 7) ^ (row & 7);
      gload_lds16(Bp + (long)row * ldb + kk + sc * 8,
                  (char*)lB + qq * 4096 + (t & ~63) * 16);
    }
    __syncthreads();                                // drains vmcnt before use
    #pragma unroll
    for (int ks = 0; ks < 2; ++ks) {                // two K=32 steps
      short8 af[FM], bfr[FN];
      #pragma unroll
      for (int i = 0; i < FM; ++i) {
        int row = wr * WM + i * 16 + (lane & 15);
        int sc = (ks * 4 + (lane >> 4)) ^ (lane & 7);
        af[i] = *(const short8*)((const char*)lA + row * 128 + sc * 16);
      }
      #pragma unroll
      for (int j = 0; j < FN; ++j) {
        int row = wc * WN + j * 16 + (lane & 15);
        int sc = (ks * 4 + (lane >> 4)) ^ (lane & 7);
        bfr[j] = *(const short8*)((const char*)lB + row * 128 + sc * 16);
      }
      #pragma unroll
      for (int i = 0; i < FM; ++i)
        #pragma unroll
        for (int j = 0; j < FN; ++j)
          acc[i][j] = __builtin_amdgcn_mfma_f32_16x16x32_bf16(af[i], bfr[j], acc[i][j], 0, 0, 0);
    }
  }

  #pragma unroll
  for (int i = 0; i < FM; ++i) {
    #pragma unroll
    for (int j = 0; j < FN; ++j) {
      long col = n0 + wc * WN + j * 16 + (lane & 15);
      float b = bias ? bias[col] : 0.f;
      #pragma unroll
      for (int r = 0; r < 4; ++r) {                 // D: row=(l>>4)*4+r, col=l&15
        long row = m0 + wr * WM + i * 16 + (lane >> 4) * 4 + r;
        float v = (acc[i][j][r] + b) * scale;
        long idx = row * ldc + col + coff;
        if (mode == 1)      ((u16*)Cv)[idx] = f2bf(v);
        else if (mode == 0) ((float*)Cv)[idx] = v;
        else                atomicAdd(&((float*)Cv)[idx], v);
      }
    }
  }
}

// fused launch: z=0 -> q, z=1 -> k, z=2 -> W2T_flat (all 1024x1024, K=1024)
__global__ __launch_bounds__(256) void gemm3_kernel(
    const u16* __restrict__ roi, const u16* __restrict__ qw,
    const u16* __restrict__ kw, const u16* __restrict__ ow,
    u16* __restrict__ q, u16* __restrict__ k, u16* __restrict__ w2t,
    const float* __restrict__ qkb)
{
  const int z = blockIdx.z;
  const u16* A = z == 2 ? ow : roi;
  const u16* B = z == 0 ? qw : z == 1 ? kw : roi;
  u16* C       = z == 0 ? q  : z == 1 ? k  : w2t;
  const float* bias = z == 0 ? qkb : z == 1 ? qkb + 1024 : nullptr;
  gemm_body<64, 64>(A, FEAT, B, FEAT, C, FEAT, 0, 1, bias, 1.0f, FEAT);
}

// final: out[n][g*64+o] += sum_m S[n*16+g][m] * W2T[g*64+o][m]
// K-split x4 (z = g*4+ks): each block K=256, f32 atomicAdd partials; bias was
// pre-written into out by cvt. 1024 blocks = 4/CU -> staging latency hidden.
__global__ __launch_bounds__(256) void final_gemm_kernel(
    const u16* __restrict__ S, const u16* __restrict__ W2T,
    float* __restrict__ out)
{
  const int g  = blockIdx.z >> 2;
  const int ks = blockIdx.z & 3;
  gemm_body<64, 64>(S + (long)g * N_ROIS + ks * 256, (long)GRP * N_ROIS,
                    W2T + (long)g * DG * N_ROIS + ks * 256, N_ROIS,
                    out, FEAT, (long)g * DG, 2, nullptr, 1.0f, 256);
}

// ---------------- aff[g][n][m] = 0.125 * sum_d q[n][g*64+d] * k[m][g*64+d] -
// K=64 -> 2 MFMAs; frags loaded directly (q,k are L2-hot).
__global__ __launch_bounds__(256) void aff_kernel(
    const u16* __restrict__ q, const u16* __restrict__ k, u16* __restrict__ aff)
{
  const int t = threadIdx.x;
  const int lane = t & 63;
  const int wave = t >> 6;
  const int g = blockIdx.z;
  const long n0 = (long)blockIdx.x * 64 + wave * 16;
  const long m0 = (long)blockIdx.y * 64;
  const u16* qp = q + (n0 + (lane & 15)) * (GRP * DG) + g * DG + (lane >> 4) * 8;
  short8 a0 = *(const short8*)qp;
  short8 a1 = *(const short8*)(qp + 32);
  f32x4 acc[4];
  #pragma unroll
  for (int mt = 0; mt < 4; ++mt) acc[mt] = (f32x4){0.f, 0.f, 0.f, 0.f};
  #pragma unroll
  for (int mt = 0; mt < 4; ++mt) {
    const u16* kp = k + (m0 + mt * 16 + (lane & 15)) * (GRP * DG) + g * DG + (lane >> 4) * 8;
    short8 b0 = *(const short8*)kp;
    short8 b1 = *(const short8*)(kp + 32);
    acc[mt] = __builtin_amdgcn_mfma_f32_16x16x32_bf16(a0, b0, acc[mt], 0, 0, 0);
    acc[mt] = __builtin_amdgcn_mfma_f32_16x16x32_bf16(a1, b1, acc[mt], 0, 0, 0);
  }
  #pragma unroll
  for (int mt = 0; mt < 4; ++mt)
    #pragma unroll
    for (int r = 0; r < 4; ++r) {
      long n = n0 + (lane >> 4) * 4 + r;
      long m = m0 + mt * 16 + (lane & 15);
      aff[((long)g << 20) + (n << 10) + m] = f2bf(acc[mt][r] * 0.125f);
    }
}

// ---------------- pf + relu + log + aff -> softmax -> S (bf16) -------------
// One block per n. pe is read exactly once across the grid (268MB = the floor).
// Thread t owns m in [4t,4t+4) for ALL 16 groups; softmax reduced via shfl+LDS.
__global__ __launch_bounds__(256) void softmax_kernel(
    const float* __restrict__ pe, const float* __restrict__ pos_w,
    const float* __restrict__ pos_b, const u16* __restrict__ aff,
    u16* __restrict__ S)
{
  __shared__ float pw[GRP * EMB];
  __shared__ float red[GRP][4];
  const int t = threadIdx.x;
  const int lane = t & 63;
  const int wave = t >> 6;
  const long n = blockIdx.x;
  const int m0 = t * 4;

  for (int i = t; i < GRP * EMB; i += 256) pw[i] = pos_w[i];

  float acc[GRP][4];
  #pragma unroll
  for (int c = 0; c < GRP; ++c) {
    float b = pos_b[c];
    acc[c][0] = b; acc[c][1] = b; acc[c][2] = b; acc[c][3] = b;
  }
  __syncthreads();

  const float* per = pe + n * N_ROIS + m0;
  #pragma unroll 4
  for (int e = 0; e < EMB; ++e) {
    float4 pv = *(const float4*)(per + (long)e * N_ROIS * N_ROIS);
    #pragma unroll
    for (int c = 0; c < GRP; ++c) {
      float w = pw[c * EMB + e];                    // broadcast, conflict-free
      acc[c][0] = fmaf(w, pv.x, acc[c][0]);
      acc[c][1] = fmaf(w, pv.y, acc[c][1]);
      acc[c][2] = fmaf(w, pv.z, acc[c][2]);
      acc[c][3] = fmaf(w, pv.w, acc[c][3]);
    }
  }

  // logits = log(max(relu(pf),1e-6)) + aff ; per-group row max
  #pragma unroll
  for (int c = 0; c < GRP; ++c) {
    ushort4 av = *(const ushort4*)(aff + ((long)c << 20) + (n << 10) + m0);
    float l0 = __logf(fmaxf(acc[c][0], 1e-6f)) + bf2f(av.x);
    float l1 = __logf(fmaxf(acc[c][1], 1e-6f)) + bf2f(av.y);
    float l2 = __logf(fmaxf(acc[c][2], 1e-6f)) + bf2f(av.z);
    float l3 = __logf(fmaxf(acc[c][3], 1e-6f)) + bf2f(av.w);
    acc[c][0] = l0; acc[c][1] = l1; acc[c][2] = l2; acc[c][3] = l3;
    float v = fmaxf(fmaxf(l0, l1), fmaxf(l2, l3));
    #pragma unroll
    for (int off = 32; off; off >>= 1) v = fmaxf(v, __shfl_xor(v, off));
    if (lane == 0) red[c][wave] = v;
  }
  __syncthreads();
  float M[GRP];
  #pragma unroll
  for (int c = 0; c < GRP; ++c)
    M[c] = fmaxf(fmaxf(red[c][0], red[c][1]), fmaxf(red[c][2], red[c][3]));
  __syncthreads();

  #pragma unroll
  for (int c = 0; c < GRP; ++c) {
    float s = 0.f;
    #pragma unroll
    for (int jj = 0; jj < 4; ++jj) {
      float p = __expf(acc[c][jj] - M[c]);
      acc[c][jj] = p;
      s += p;
    }
    #pragma unroll
    for (int off = 32; off; off >>= 1) s += __shfl_xor(s, off);
    if (lane == 0) red[c][wave] = s;
  }
  __syncthreads();
  #pragma unroll
  for (int c = 0; c < GRP; ++c) {
    float s = red[c][0] + red[c][1] + red[c][2] + red[c][3];
    float r = 1.0f / s;
    ushort4 o;
    o.x = f2bf(acc[c][0] * r); o.y = f2bf(acc[c][1] * r);
    o.z = f2bf(acc[c][2] * r); o.w = f2bf(acc[c][3] * r);
    *(ushort4*)(S + (n << 14) + ((long)c << 10) + m0) = o;
  }
}

// ---------------------------------------------------------------------------
extern "C" void kernel_launch(void* const* d_in, const int* in_sizes, int n_in,
                              void* d_out, int out_size, void* d_ws, size_t ws_size,
                              hipStream_t stream)
{
  const float* roi   = (const float*)d_in[0];
  const float* pe    = (const float*)d_in[1];
  // d_in[2] = nongt_dim (always 1024 here)
  const float* pos_w = (const float*)d_in[3];
  const float* pos_b = (const float*)d_in[4];
  const float* q_w   = (const float*)d_in[5];
  const float* q_b   = (const float*)d_in[6];
  const float* k_w   = (const float*)d_in[7];
  const float* k_b   = (const float*)d_in[8];
  const float* out_w = (const float*)d_in[9];
  const float* out_b = (const float*)d_in[10];
  float* out = (float*)d_out;

  const long M1 = 1l << 20;
  u16* roi_bf = (u16*)d_ws;                  // [1024][1024]
  u16* qw_bf  = roi_bf + M1;                 // [1024][1024]
  u16* kw_bf  = qw_bf  + M1;
  u16* ow_bf  = kw_bf  + M1;
  u16* q_bf   = ow_bf  + M1;                 // [n][1024]
  u16* k_bf   = q_bf   + M1;
  u16* aff_bf = k_bf   + M1;                 // [16][1024][1024]
  u16* S_bf   = aff_bf + 16 * M1;            // [1024][16][1024]
  u16* W2T    = S_bf   + 16 * M1;            // [16*64][1024] (flat go x m)
  float* qkb  = (float*)(W2T + M1);          // [2048] = [q_b; k_b]

  // cvt + qkb gather + out bias-init (final gemm atomicAdds onto it)
  cvt_kernel<<<5121, 256, 0, stream>>>(roi, q_w, k_w, out_w,
                                       roi_bf, qw_bf, kw_bf, ow_bf,
                                       q_b, k_b, qkb, out_b, out);

  // one launch, 768 blocks: q = roi@qw^T+qb, k = roi@kw^T+kb,
  // W2T[g*64+o][m] = sum_f out_w[g*64+o][f]*roi[m][f]
  gemm3_kernel<<<dim3(16, 16, 3), 256, 0, stream>>>(
      roi_bf, qw_bf, kw_bf, ow_bf, q_bf, k_bf, W2T, qkb);

  aff_kernel<<<dim3(16, 16, 16), 256, 0, stream>>>(q_bf, k_bf, aff_bf);

  softmax_kernel<<<1024, 256, 0, stream>>>(pe, pos_w, pos_b, aff_bf, S_bf);

  // out += S @ W2T^T per group, K-split x4, atomicAdd f32
  final_gemm_kernel<<<dim3(16, 1, 64), 256, 0, stream>>>(S_bf, W2T, out);
}